// Round 7
// baseline (55.386 us; speedup 1.0000x reference)
//
#include <hip/hip_runtime.h>

// score[e] = dot(h[src[e]], h[dst[e]]), D=32.
// Two-phase plane-split: h converted once to bf16 into TWO planes in d_ws,
//   hb0[node][0:16]  (3.2 MB)  and  hb1[node][16:32] (3.2 MB),
// each of which FITS in a 4 MB per-XCD L2 (the full 6.4 MB table did not ->
// capacity misses crossing the ~3.3 TB/s random-line fabric path were the
// bound). Edge kernel: 2 lanes/edge, indices + partial sums held in registers
// across phases (fully unrolled, static indexing); phase 1 gathers plane 0
// for all this group's edges, phase 2 gathers plane 1, completes the dot.

constexpr int D_FEAT  = 32;
constexpr int HALF_SH = 16;   // shorts per row-half (32 B)
constexpr int GRID    = 2048;
constexpr int BLOCK   = 256;
constexpr int MAX_IT  = 8;    // MAX_IT * GRID*BLOCK/2 = 2.09M >= n_edges

typedef float          f32x4 __attribute__((ext_vector_type(4)));
typedef unsigned int   u32x4 __attribute__((ext_vector_type(4)));
typedef unsigned short u16x4 __attribute__((ext_vector_type(4)));

static __device__ __forceinline__ float bf_lo(unsigned u) {
    return __uint_as_float(u << 16);
}
static __device__ __forceinline__ float bf_hi(unsigned u) {
    return __uint_as_float(u & 0xffff0000u);
}
static __device__ __forceinline__ unsigned short f2bf_rne(float f) {
    unsigned u = __float_as_uint(f);
    u = (u + 0x7fffu + ((u >> 16) & 1u)) >> 16;  // round-nearest-even
    return (unsigned short)u;
}

static __device__ __forceinline__ float dot8(u32x4 a, u32x4 b) {
    float acc;
    acc  = bf_lo(a.x) * bf_lo(b.x) + bf_hi(a.x) * bf_hi(b.x);
    acc += bf_lo(a.y) * bf_lo(b.y) + bf_hi(a.y) * bf_hi(b.y);
    acc += bf_lo(a.z) * bf_lo(b.z) + bf_hi(a.z) * bf_hi(b.z);
    acc += bf_lo(a.w) * bf_lo(b.w) + bf_hi(a.w) * bf_hi(b.w);
    return acc;
}

// Convert h (f32 [N][32]) into two bf16 planes: hb0 = cols 0..15, hb1 = 16..31.
// Chunk i (f32x4): node = i>>3, q = i&7; plane = q>>2, 8B-chunk = q&3.
__global__ void __launch_bounds__(256) convert_h_planes(
    const f32x4* __restrict__ h4,
    unsigned short* __restrict__ hb0,
    unsigned short* __restrict__ hb1,
    int n4)
{
    int i = blockIdx.x * blockDim.x + threadIdx.x;
    const int stride = gridDim.x * blockDim.x;
    for (; i < n4; i += stride) {
        const f32x4 v = __builtin_nontemporal_load(&h4[i]);
        u16x4 o;
        o.x = f2bf_rne(v.x);
        o.y = f2bf_rne(v.y);
        o.z = f2bf_rne(v.z);
        o.w = f2bf_rne(v.w);
        const int node = i >> 3;
        const int q = i & 7;
        unsigned short* base = (q < 4) ? hb0 : hb1;
        *reinterpret_cast<u16x4*>(base + (size_t)node * HALF_SH + (q & 3) * 4) = o;
    }
}

__global__ void __launch_bounds__(256) edge_dot_2phase(
    const unsigned short* __restrict__ hb0,
    const unsigned short* __restrict__ hb1,
    const int* __restrict__ src,
    const int* __restrict__ dst,
    float* __restrict__ out,
    int n_edges)
{
    const int g = threadIdx.x & 1;                     // lane-in-pair: 16 B slice
    const int group = (blockIdx.x * blockDim.x + threadIdx.x) >> 1;
    const int n_groups = (GRID * BLOCK) >> 1;

    int   sv[MAX_IT], dv[MAX_IT];
    float acc[MAX_IT];

    // Phase 1: indices + plane-0 partial dots (plane 0 hot in L2)
    #pragma unroll
    for (int it = 0; it < MAX_IT; ++it) {
        const int e = group + it * n_groups;
        acc[it] = 0.f;
        sv[it] = 0; dv[it] = 0;
        if (e < n_edges) {
            const int s = __builtin_nontemporal_load(&src[e]);
            const int d = __builtin_nontemporal_load(&dst[e]);
            sv[it] = s; dv[it] = d;
            const u32x4 a = *reinterpret_cast<const u32x4*>(
                hb0 + (size_t)s * HALF_SH + g * 8);
            const u32x4 b = *reinterpret_cast<const u32x4*>(
                hb0 + (size_t)d * HALF_SH + g * 8);
            acc[it] = dot8(a, b);
        }
    }

    // Phase 2: plane-1 partial dots with saved indices (plane 1 hot in L2)
    #pragma unroll
    for (int it = 0; it < MAX_IT; ++it) {
        const int e = group + it * n_groups;
        if (e < n_edges) {
            const u32x4 a = *reinterpret_cast<const u32x4*>(
                hb1 + (size_t)sv[it] * HALF_SH + g * 8);
            const u32x4 b = *reinterpret_cast<const u32x4*>(
                hb1 + (size_t)dv[it] * HALF_SH + g * 8);
            float t = acc[it] + dot8(a, b);
            t += __shfl_xor(t, 1);
            if (g == 0) __builtin_nontemporal_store(t, &out[e]);
        }
    }
}

// f32 fallback (if ws too small for the bf16 planes)
__global__ void __launch_bounds__(256) edge_dot_f32(
    const float* __restrict__ h,
    const int* __restrict__ src,
    const int* __restrict__ dst,
    float* __restrict__ out,
    int n_edges)
{
    const int g = threadIdx.x & 7;
    const int group = (blockIdx.x * blockDim.x + threadIdx.x) >> 3;
    const int n_groups = (gridDim.x * blockDim.x) >> 3;
    for (int e = group; e < n_edges; e += n_groups) {
        const int s = src[e];
        const int d = dst[e];
        const f32x4 a = reinterpret_cast<const f32x4*>(h + (size_t)s * D_FEAT)[g];
        const f32x4 b = reinterpret_cast<const f32x4*>(h + (size_t)d * D_FEAT)[g];
        float acc = a.x * b.x + a.y * b.y + a.z * b.z + a.w * b.w;
        acc += __shfl_xor(acc, 1);
        acc += __shfl_xor(acc, 2);
        acc += __shfl_xor(acc, 4);
        if (g == 0) out[e] = acc;
    }
}

extern "C" void kernel_launch(void* const* d_in, const int* in_sizes, int n_in,
                              void* d_out, int out_size, void* d_ws, size_t ws_size,
                              hipStream_t stream) {
    const float* h   = (const float*)d_in[0];
    const int*   src = (const int*)d_in[1];
    const int*   dst = (const int*)d_in[2];
    float*       out = (float*)d_out;
    const int n_h     = in_sizes[0];           // N_NODES * D_FEAT
    const int n_edges = in_sizes[1];
    const int n_nodes = n_h / D_FEAT;

    const size_t plane_bytes = (size_t)n_nodes * HALF_SH * sizeof(unsigned short);
    if (ws_size >= 2 * plane_bytes &&
        (size_t)n_edges <= (size_t)MAX_IT * (GRID * BLOCK / 2)) {
        unsigned short* hb0 = (unsigned short*)d_ws;
        unsigned short* hb1 = hb0 + (size_t)n_nodes * HALF_SH;
        const int n4 = n_h / 4;
        convert_h_planes<<<GRID, BLOCK, 0, stream>>>(
            (const f32x4*)h, hb0, hb1, n4);
        edge_dot_2phase<<<GRID, BLOCK, 0, stream>>>(
            hb0, hb1, src, dst, out, n_edges);
    } else {
        edge_dot_f32<<<2048, 256, 0, stream>>>(h, src, dst, out, n_edges);
    }
}

// Round 8
// 51.941 us; speedup vs baseline: 1.0663x; 1.0663x over previous
//
#include <hip/hip_runtime.h>

// score[e] = dot(h[src[e]], h[dst[e]]), D=32.
// Sequential-phase plane split: h converted once to bf16 into two contiguous
// planes in d_ws (hb0 = cols 0..15, hb1 = cols 16..31; 3.2 MB each -> each
// plane fits every per-XCD 4 MB L2). Then TWO sequential edge kernels:
//   A: out[e]  = dot16(hb0[src], hb0[dst])   (only plane 0 live chip-wide)
//   B: out[e] += dot16(hb1[src], hb1[dst])   (only plane 1 live chip-wide)
// Kernel-granularity phasing gives the global phase separation r7's in-kernel
// phasing lacked; contiguous planes keep fill = 3.2 MB per phase.
// Gather shape: 4 lanes/edge x 8 B (16 distinct lines/instr, r2's proven
// divergence profile), 2-step shfl reduce, coalesced index loads and stores.

constexpr int D_FEAT  = 32;
constexpr int HALF_SH = 16;   // shorts per plane row (32 B)
constexpr int GRID    = 2048;
constexpr int BLOCK   = 256;

typedef float          f32x4 __attribute__((ext_vector_type(4)));
typedef unsigned int   u32x2 __attribute__((ext_vector_type(2)));
typedef unsigned short u16x4 __attribute__((ext_vector_type(4)));

static __device__ __forceinline__ float bf_lo(unsigned u) {
    return __uint_as_float(u << 16);
}
static __device__ __forceinline__ float bf_hi(unsigned u) {
    return __uint_as_float(u & 0xffff0000u);
}
static __device__ __forceinline__ unsigned short f2bf_rne(float f) {
    unsigned u = __float_as_uint(f);
    u = (u + 0x7fffu + ((u >> 16) & 1u)) >> 16;  // round-nearest-even
    return (unsigned short)u;
}

// h (f32 [N][32]) -> two bf16 planes: hb0 = cols 0..15, hb1 = cols 16..31.
// f32x4 chunk i: node = i>>3, q = i&7; plane = q>>2, 8-B subchunk = q&3.
__global__ void __launch_bounds__(256) convert_h_planes(
    const f32x4* __restrict__ h4,
    unsigned short* __restrict__ hb0,
    unsigned short* __restrict__ hb1,
    int n4)
{
    int i = blockIdx.x * blockDim.x + threadIdx.x;
    const int stride = gridDim.x * blockDim.x;
    for (; i < n4; i += stride) {
        const f32x4 v = h4[i];
        u16x4 o;
        o.x = f2bf_rne(v.x);
        o.y = f2bf_rne(v.y);
        o.z = f2bf_rne(v.z);
        o.w = f2bf_rne(v.w);
        const int node = i >> 3;
        const int q = i & 7;
        unsigned short* base = (q < 4) ? hb0 : hb1;
        *reinterpret_cast<u16x4*>(base + (size_t)node * HALF_SH + (q & 3) * 4) = o;
    }
}

// One plane's partial dot for all edges. ADD=false: out[e] = partial;
// ADD=true: out[e] += partial (read-modify-write, each e owned by one group).
template <bool ADD>
__global__ void __launch_bounds__(256) edge_plane(
    const unsigned short* __restrict__ hb,  // plane base (3.2 MB)
    const int* __restrict__ src,
    const int* __restrict__ dst,
    float* __restrict__ out,
    int n_edges)
{
    const int g = threadIdx.x & 3;  // 4 lanes/edge, 8 B each (32-B plane row)
    const int group = (blockIdx.x * blockDim.x + threadIdx.x) >> 2;
    const int n_groups = (GRID * BLOCK) >> 2;

    for (int e = group; e < n_edges; e += n_groups) {
        const int s = src[e];
        const int d = dst[e];
        const u32x2 a = *reinterpret_cast<const u32x2*>(
            hb + (size_t)s * HALF_SH + g * 4);
        const u32x2 b = *reinterpret_cast<const u32x2*>(
            hb + (size_t)d * HALF_SH + g * 4);
        float acc = bf_lo(a.x) * bf_lo(b.x) + bf_hi(a.x) * bf_hi(b.x)
                  + bf_lo(a.y) * bf_lo(b.y) + bf_hi(a.y) * bf_hi(b.y);
        acc += __shfl_xor(acc, 1);
        acc += __shfl_xor(acc, 2);
        if (g == 0) {
            if (ADD) out[e] += acc;
            else     out[e] = acc;
        }
    }
}

// f32 fallback (if ws too small for the bf16 planes)
__global__ void __launch_bounds__(256) edge_dot_f32(
    const float* __restrict__ h,
    const int* __restrict__ src,
    const int* __restrict__ dst,
    float* __restrict__ out,
    int n_edges)
{
    const int g = threadIdx.x & 7;
    const int group = (blockIdx.x * blockDim.x + threadIdx.x) >> 3;
    const int n_groups = (gridDim.x * blockDim.x) >> 3;
    for (int e = group; e < n_edges; e += n_groups) {
        const int s = src[e];
        const int d = dst[e];
        const f32x4 a = reinterpret_cast<const f32x4*>(h + (size_t)s * D_FEAT)[g];
        const f32x4 b = reinterpret_cast<const f32x4*>(h + (size_t)d * D_FEAT)[g];
        float acc = a.x * b.x + a.y * b.y + a.z * b.z + a.w * b.w;
        acc += __shfl_xor(acc, 1);
        acc += __shfl_xor(acc, 2);
        acc += __shfl_xor(acc, 4);
        if (g == 0) out[e] = acc;
    }
}

extern "C" void kernel_launch(void* const* d_in, const int* in_sizes, int n_in,
                              void* d_out, int out_size, void* d_ws, size_t ws_size,
                              hipStream_t stream) {
    const float* h   = (const float*)d_in[0];
    const int*   src = (const int*)d_in[1];
    const int*   dst = (const int*)d_in[2];
    float*       out = (float*)d_out;
    const int n_h     = in_sizes[0];           // N_NODES * D_FEAT
    const int n_edges = in_sizes[1];
    const int n_nodes = n_h / D_FEAT;

    const size_t plane_bytes = (size_t)n_nodes * HALF_SH * sizeof(unsigned short);
    if (ws_size >= 2 * plane_bytes) {
        unsigned short* hb0 = (unsigned short*)d_ws;
        unsigned short* hb1 = hb0 + (size_t)n_nodes * HALF_SH;
        const int n4 = n_h / 4;
        convert_h_planes<<<GRID, BLOCK, 0, stream>>>(
            (const f32x4*)h, hb0, hb1, n4);
        edge_plane<false><<<GRID, BLOCK, 0, stream>>>(
            hb0, src, dst, out, n_edges);
        edge_plane<true><<<GRID, BLOCK, 0, stream>>>(
            hb1, src, dst, out, n_edges);
    } else {
        edge_dot_f32<<<2048, 256, 0, stream>>>(h, src, dst, out, n_edges);
    }
}